// Round 9
// baseline (886.982 us; speedup 1.0000x reference)
//
#include <hip/hip_runtime.h>
#include <math.h>

// Problem constants
#define Bc 4
#define Tc 1024
#define DMc 1024
#define Hc 16
#define DKc 64
#define BHc 64          // B*H
#define Mc 4096         // B*T
#define TD (Tc*DKc)     // 65536 el per (b,h) slab, stride-64 layout
#define TD2 (Tc*128)    // combined re|im slab, stride-128 layout
#define TDS (128*2048)  // split-D slab: [d(128)][s hi 1024 | s lo 1024] bf16

typedef __bf16 bf16_t;
typedef bf16_t bf16x4 __attribute__((ext_vector_type(4)));
typedef bf16_t bf16x8 __attribute__((ext_vector_type(8)));
typedef float  f32x4  __attribute__((ext_vector_type(4)));

#define GSTR 40    // mgemm: LDS stride for 32-wide rows (80 B)
#define KLSTR 136  // prop: K tile row stride (bf16): [hi 64|lo 64|pad 8]
#define DLSTR 72   // prop: D tile row stride (bf16): [hi 32|lo 32|pad 8]

__device__ __forceinline__ bf16x8 ld8(const bf16_t* p) {
    union { bf16x8 v; struct { bf16x4 a, b; } s; } u;
    u.s.a = *(const bf16x4*)p;
    u.s.b = *(const bf16x4*)(p + 4);
    return u.v;
}
__device__ __forceinline__ void packsplit4(bf16_t* dh, bf16_t* dl, float4 v) {
    bf16x4 h, l;
    h[0]=(bf16_t)v.x; l[0]=(bf16_t)(v.x-(float)h[0]);
    h[1]=(bf16_t)v.y; l[1]=(bf16_t)(v.y-(float)h[1]);
    h[2]=(bf16_t)v.z; l[2]=(bf16_t)(v.z-(float)h[2]);
    h[3]=(bf16_t)v.w; l[3]=(bf16_t)(v.w-(float)h[3]);
    *(bf16x4*)dh = h; *(bf16x4*)dl = l;
}
__device__ __forceinline__ unsigned pk2(bf16_t a, bf16_t b) {
    unsigned short ua = __builtin_bit_cast(unsigned short, a);
    unsigned short ub = __builtin_bit_cast(unsigned short, b);
    return (unsigned)ua | ((unsigned)ub << 16);
}

// ---------------------------------------------------------------------------
// Convert x (4096x1024 f32) -> xh, xl bf16
// ---------------------------------------------------------------------------
__global__ __launch_bounds__(256)
void convx_k(const float* __restrict__ x,
             bf16_t* __restrict__ xh, bf16_t* __restrict__ xl)
{
    size_t i = ((size_t)blockIdx.x * 256 + threadIdx.x) * 4;
    float4 v = *(const float4*)&x[i];
    packsplit4(&xh[i], &xl[i], v);
}

// ---------------------------------------------------------------------------
// Convert + transpose each W (1024x1024 f32 [k][n]) -> WT hi/lo bf16 [n][k].
// ---------------------------------------------------------------------------
__global__ __launch_bounds__(256)
void convw_k(const float* __restrict__ W0, const float* __restrict__ W1,
             const float* __restrict__ W2, const float* __restrict__ W3,
             const float* __restrict__ W4, const float* __restrict__ W5,
             bf16_t* __restrict__ WT)
{
    __shared__ float tile[32][33];
    const float* Ws[6] = {W0, W1, W2, W3, W4, W5};
    const int wi = blockIdx.z;
    const float* W = Ws[wi];
    bf16_t* WTh = WT + (size_t)wi * 2097152;
    bf16_t* WTl = WTh + 1048576;

    const int tx = threadIdx.x & 31, ty = threadIdx.x >> 5;
    const int k0 = blockIdx.x * 32, n0 = blockIdx.y * 32;
#pragma unroll
    for (int i = 0; i < 4; i++)
        tile[ty + 8*i][tx] = W[(size_t)(k0 + ty + 8*i) * DMc + n0 + tx];
    __syncthreads();
    const int kg = threadIdx.x & 7, n = threadIdx.x >> 3;
    float4 v = make_float4(tile[kg*4+0][n], tile[kg*4+1][n],
                           tile[kg*4+2][n], tile[kg*4+3][n]);
    const size_t o = (size_t)(n0 + n) * DMc + k0 + kg*4;
    packsplit4(&WTh[o], &WTl[o], v);
}

// ---------------------------------------------------------------------------
// Split-bf16 MFMA GEMM (3 products, f32 accum). A [m][k] hi/lo; B = WT [n][k].
// MODE 0: sel 0->Qs split [bh][t][hi64|lo64]; 1->Ks same;
//         2,3 -> DT0 split-transposed [bh][d][s hi|lo] (re d 0-63 / im 64-127);
//         4 -> V f32 [bh][t][64].
// MODE 1: K-split x4 (blockIdx.z selects K=256 slice), f32 partial at
//         Of + z*4M floats (CONTIGUOUS slices); reduced by reduce4_k.
// ---------------------------------------------------------------------------
template<int MODE>
__global__ __launch_bounds__(256)
void mgemm_k(const bf16_t* __restrict__ Ah, const bf16_t* __restrict__ Al,
             const bf16_t* __restrict__ WT,
             bf16_t* __restrict__ Oq, bf16_t* __restrict__ Ok,
             bf16_t* __restrict__ Od, float* __restrict__ Ov,
             float* __restrict__ Of)
{
    __shared__ bf16_t Ash[128*GSTR], Asl[128*GSTR];
    __shared__ bf16_t Bsh[128*GSTR], Bsl[128*GSTR];

    const int tid = threadIdx.x;
    const int wv  = tid >> 6;
    const int ln  = tid & 63;
    const int l15 = ln & 15;
    const int qd  = ln >> 4;
    const int m0  = blockIdx.x * 128;
    const int by  = blockIdx.y;

    const bf16_t *Bh, *Bl;
    int n0, sel, kt0, kt1;
    float* Opart;
    if (MODE == 0) {
        sel = by >> 3;
        n0 = (by & 7) * 128;
        Bh = WT + (size_t)sel * 2097152;
        Bl = Bh + 1048576;
        kt0 = 0; kt1 = DMc;
        Opart = nullptr;
    } else {
        sel = 5;
        Bh = WT + (size_t)5 * 2097152;
        Bl = Bh + 1048576;
        n0 = by * 128;
        kt0 = blockIdx.z * 256; kt1 = kt0 + 256;
        Opart = Of + (size_t)blockIdx.z * ((size_t)Mc * DMc);
    }

    const int srow  = tid >> 1;
    const int shalf = (tid & 1) * 16;

    f32x4 acc[4][4];
#pragma unroll
    for (int i = 0; i < 4; i++)
#pragma unroll
        for (int j = 0; j < 4; j++) acc[i][j] = (f32x4)0.f;

#pragma unroll 1
    for (int kt = kt0; kt < kt1; kt += 32) {
        __syncthreads();
        {
            const size_t ga = (size_t)(m0 + srow) * DMc + kt + shalf;
            bf16x8 a0 = *(const bf16x8*)&Ah[ga];
            bf16x8 a1 = *(const bf16x8*)&Ah[ga + 8];
            bf16x8 a2 = *(const bf16x8*)&Al[ga];
            bf16x8 a3 = *(const bf16x8*)&Al[ga + 8];
            const size_t gb = (size_t)(n0 + srow) * DMc + kt + shalf;
            bf16x8 b0 = *(const bf16x8*)&Bh[gb];
            bf16x8 b1 = *(const bf16x8*)&Bh[gb + 8];
            bf16x8 b2 = *(const bf16x8*)&Bl[gb];
            bf16x8 b3 = *(const bf16x8*)&Bl[gb + 8];
            const int lo = srow * GSTR + shalf;
            *(bf16x8*)&Ash[lo]     = a0;
            *(bf16x8*)&Ash[lo + 8] = a1;
            *(bf16x8*)&Asl[lo]     = a2;
            *(bf16x8*)&Asl[lo + 8] = a3;
            *(bf16x8*)&Bsh[lo]     = b0;
            *(bf16x8*)&Bsh[lo + 8] = b1;
            *(bf16x8*)&Bsl[lo]     = b2;
            *(bf16x8*)&Bsl[lo + 8] = b3;
        }
        __syncthreads();

        bf16x8 fah[4], fal[4], fbh[4], fbl[4];
#pragma unroll
        for (int it = 0; it < 4; it++) {
            const int row = ((wv>>1)*64 + it*16 + l15) * GSTR + qd*8;
            fah[it] = ld8(&Ash[row]);
            fal[it] = ld8(&Asl[row]);
        }
#pragma unroll
        for (int jt = 0; jt < 4; jt++) {
            const int row = ((wv&1)*64 + jt*16 + l15) * GSTR + qd*8;
            fbh[jt] = ld8(&Bsh[row]);
            fbl[jt] = ld8(&Bsl[row]);
        }
#pragma unroll
        for (int it = 0; it < 4; it++)
#pragma unroll
            for (int jt = 0; jt < 4; jt++) {
                acc[it][jt] = __builtin_amdgcn_mfma_f32_16x16x32_bf16(
                    fah[it], fbh[jt], acc[it][jt], 0, 0, 0);
                acc[it][jt] = __builtin_amdgcn_mfma_f32_16x16x32_bf16(
                    fah[it], fbl[jt], acc[it][jt], 0, 0, 0);
                acc[it][jt] = __builtin_amdgcn_mfma_f32_16x16x32_bf16(
                    fal[it], fbh[jt], acc[it][jt], 0, 0, 0);
            }
    }

#pragma unroll
    for (int it = 0; it < 4; it++) {
        const int mb = m0 + (wv>>1)*64 + it*16 + qd*4;
#pragma unroll
        for (int jt = 0; jt < 4; jt++) {
            const int col = n0 + (wv&1)*64 + jt*16 + l15;
            if (MODE == 0) {
                const int hh = col >> 6;
                const int b  = mb >> 10, t0 = mb & 1023;
                if (sel <= 1) {
                    bf16_t* O = sel ? Ok : Oq;
                    const int d = col & 63;
#pragma unroll
                    for (int r = 0; r < 4; r++) {
                        const float val = acc[it][jt][r];
                        const size_t o = ((size_t)(b*Hc + hh)*Tc + t0 + r)*128 + d;
                        bf16_t vh = (bf16_t)val;
                        O[o]      = vh;
                        O[o + 64] = (bf16_t)(val - (float)vh);
                    }
                } else if (sel <= 3) {
                    // transposed split-D: [bh][d][t hi | t lo]
                    const int d = (sel == 3 ? 64 : 0) + (col & 63);
                    bf16x4 h4, l4;
#pragma unroll
                    for (int r = 0; r < 4; r++) {
                        const float val = acc[it][jt][r];
                        h4[r] = (bf16_t)val;
                        l4[r] = (bf16_t)(val - (float)h4[r]);
                    }
                    const size_t o = (size_t)(b*Hc + hh)*TDS + (size_t)d*2048 + t0;
                    *(bf16x4*)&Od[o]        = h4;
                    *(bf16x4*)&Od[o + 1024] = l4;
                } else {
#pragma unroll
                    for (int r = 0; r < 4; r++)
                        Ov[((size_t)(b*Hc + hh)*Tc + t0 + r)*64 + (col & 63)]
                            = acc[it][jt][r];
                }
            } else {
#pragma unroll
                for (int r = 0; r < 4; r++)
                    Opart[(size_t)(mb + r) * DMc + col] = acc[it][jt][r];
            }
        }
    }
}

// ---------------------------------------------------------------------------
// Sum 4 K-slice partials -> out
// ---------------------------------------------------------------------------
__global__ __launch_bounds__(256)
void reduce4_k(const float* __restrict__ p0, const float* __restrict__ p1,
               const float* __restrict__ p2, const float* __restrict__ p3,
               float* __restrict__ out)
{
    size_t i = ((size_t)blockIdx.x * 256 + threadIdx.x) * 4;
    float4 a = *(const float4*)&p0[i];
    float4 b = *(const float4*)&p1[i];
    float4 c = *(const float4*)&p2[i];
    float4 d = *(const float4*)&p3[i];
    *(float4*)&out[i] = make_float4(a.x+b.x+c.x+d.x, a.y+b.y+c.y+d.y,
                                    a.z+b.z+c.z+d.z, a.w+b.w+c.w+d.w);
}

// ---------------------------------------------------------------------------
// Fused propagation step: split-bf16 MFMA, 64-t blocks (4 blocks/CU).
// K/D tiles staged in LDS (pure 16B copies of pre-split data); scores
// computed transposed (A=K, B=Q -> C[s][t]) with Q fragments in registers;
// P stays in registers, moved to B-operand layout via __shfl (verified r6).
// Each wave owns 16 t's end-to-end. 2 barriers per 32-s chunk.
// Layouts: Q/K [bh][t|s][hi64|lo64]; D [bh][d 0..127][s hi 1024 | s lo 1024].
// FINAL=0: out split-D slab.  FINAL=1: out Dc f32 [bh][t][128].
// ---------------------------------------------------------------------------
template<int FINAL>
__global__ __launch_bounds__(256)
void prop_k(const bf16_t* __restrict__ Qg, const bf16_t* __restrict__ Kg,
            const bf16_t* __restrict__ DTin, bf16_t* __restrict__ DTout,
            float* __restrict__ Dc, const float* __restrict__ llam)
{
    __shared__ bf16_t Ks[32*KLSTR];    // 8.7 KB: [s][dk hi 64 | dk lo 64 | pad]
    __shared__ bf16_t Ds[128*DLSTR];   // 18.4 KB: [d][s hi 32 | s lo 32 | pad]

    const int tid = threadIdx.x;
    const int wv  = tid >> 6;
    const int ln  = tid & 63;
    const int l15 = ln & 15;
    const int qd  = ln >> 4;
    const int bh  = blockIdx.x;
    const int Tw  = blockIdx.y * 64 + wv * 16;   // this wave's 16 t's

    const bf16_t* Qh  = Qg   + (size_t)bh * (Tc*128);
    const bf16_t* Kh  = Kg   + (size_t)bh * (Tc*128);
    const bf16_t* DTh = DTin + (size_t)bh * TDS;

    // Q B-fragments (lane n=t=l15, k=dk=qd*8+j), loop-invariant
    bf16x8 qfh[2], qfl[2];     // [ks]
    {
        const bf16_t* qp = &Qh[(size_t)(Tw + l15) * 128];
#pragma unroll
        for (int ks = 0; ks < 2; ks++) {
            qfh[ks] = *(const bf16x8*)&qp[ks*32 + qd*8];
            qfl[ks] = *(const bf16x8*)&qp[64 + ks*32 + qd*8];
        }
    }

    f32x4 acc[8];                 // [d-tile]
#pragma unroll
    for (int i = 0; i < 8; i++) acc[i] = (f32x4)0.f;
    float rs = 0.f;

    // shfl source lanes for the P layout transform (verified r6)
    const int srcA = (((qd & 1) * 2)     << 4) | l15;
    const int srcB = (((qd & 1) * 2 + 1) << 4) | l15;
    const bool loQuad = (qd < 2);

#pragma unroll 1
    for (int ch = 0; ch < 32; ch++) {
        const int s0 = ch * 32;
        // ---- stage K chunk (32 x [hi64|lo64], contiguous in global)
#pragma unroll
        for (int i = 0; i < 2; i++) {
            int id = tid + i*256;
            int r = id >> 4, sg = id & 15;
            *(bf16x8*)&Ks[r*KLSTR + sg*8] =
                *(const bf16x8*)&Kh[(size_t)(s0 + r)*128 + sg*8];
        }
        // ---- stage D chunk (128 x [s hi 32 | s lo 32])
#pragma unroll
        for (int i = 0; i < 4; i++) {
            int id = tid + i*256;
            int r = id >> 3, sg = id & 7;
            const bf16_t* src = (sg < 4)
                ? &DTh[(size_t)r*2048 + s0 + sg*8]
                : &DTh[(size_t)r*2048 + 1024 + s0 + (sg-4)*8];
            bf16_t* dst = (sg < 4) ? &Ds[r*DLSTR + sg*8]
                                   : &Ds[r*DLSTR + 32 + (sg-4)*8];
            *(bf16x8*)dst = *(const bf16x8*)src;
        }
        __syncthreads();
        // ---- K A-fragments from LDS (lane m=s=si*16+l15, k=dk)
        bf16x8 kfh[2][2], kfl[2][2];   // [si][ks]
#pragma unroll
        for (int si = 0; si < 2; si++) {
            const int row = (si*16 + l15) * KLSTR;
#pragma unroll
            for (int ks = 0; ks < 2; ks++) {
                kfh[si][ks] = ld8(&Ks[row + ks*32 + qd*8]);
                kfl[si][ks] = ld8(&Ks[row + 64 + ks*32 + qd*8]);
            }
        }
        // ---- scores^T: C[m=s][n=t]
        f32x4 pacc[2];              // [si]
#pragma unroll
        for (int si = 0; si < 2; si++) pacc[si] = (f32x4)0.f;
#pragma unroll
        for (int ks = 0; ks < 2; ks++)
#pragma unroll
            for (int si = 0; si < 2; si++) {
                pacc[si] = __builtin_amdgcn_mfma_f32_16x16x32_bf16(
                    kfh[si][ks], qfh[ks], pacc[si], 0, 0, 0);
                pacc[si] = __builtin_amdgcn_mfma_f32_16x16x32_bf16(
                    kfl[si][ks], qfh[ks], pacc[si], 0, 0, 0);
                pacc[si] = __builtin_amdgcn_mfma_f32_16x16x32_bf16(
                    kfh[si][ks], qfl[ks], pacc[si], 0, 0, 0);
            }
        // ---- exp + split + pack (lane holds s = si*16 + qd*4 + r for t=l15)
        unsigned pk01h[2], pk23h[2], pk01l[2], pk23l[2]; // [si]
#pragma unroll
        for (int si = 0; si < 2; si++) {
            float e0 = __expf(pacc[si][0] * 0.125f);
            float e1 = __expf(pacc[si][1] * 0.125f);
            float e2 = __expf(pacc[si][2] * 0.125f);
            float e3 = __expf(pacc[si][3] * 0.125f);
            rs += (e0 + e1) + (e2 + e3);
            bf16_t h0=(bf16_t)e0, h1=(bf16_t)e1, h2=(bf16_t)e2, h3=(bf16_t)e3;
            pk01h[si] = pk2(h0, h1);
            pk23h[si] = pk2(h2, h3);
            pk01l[si] = pk2((bf16_t)(e0-(float)h0), (bf16_t)(e1-(float)h1));
            pk23l[si] = pk2((bf16_t)(e2-(float)h2), (bf16_t)(e3-(float)h3));
        }
        // ---- P -> B-operand fragment via shfl (dest: n=t=l15, k=s=qd*8+j)
        bf16x8 pfh, pfl;
        {
            union { bf16x8 v; unsigned u[4]; } H, L;
            unsigned a0 = __shfl((int)pk01h[0], srcA, 64);
            unsigned a1 = __shfl((int)pk23h[0], srcA, 64);
            unsigned a2 = __shfl((int)pk01h[0], srcB, 64);
            unsigned a3 = __shfl((int)pk23h[0], srcB, 64);
            unsigned b0 = __shfl((int)pk01h[1], srcA, 64);
            unsigned b1 = __shfl((int)pk23h[1], srcA, 64);
            unsigned b2 = __shfl((int)pk01h[1], srcB, 64);
            unsigned b3 = __shfl((int)pk23h[1], srcB, 64);
            H.u[0] = loQuad ? a0 : b0;  H.u[1] = loQuad ? a1 : b1;
            H.u[2] = loQuad ? a2 : b2;  H.u[3] = loQuad ? a3 : b3;
            unsigned c0 = __shfl((int)pk01l[0], srcA, 64);
            unsigned c1 = __shfl((int)pk23l[0], srcA, 64);
            unsigned c2 = __shfl((int)pk01l[0], srcB, 64);
            unsigned c3 = __shfl((int)pk23l[0], srcB, 64);
            unsigned d0_ = __shfl((int)pk01l[1], srcA, 64);
            unsigned d1 = __shfl((int)pk23l[1], srcA, 64);
            unsigned d2 = __shfl((int)pk01l[1], srcB, 64);
            unsigned d3 = __shfl((int)pk23l[1], srcB, 64);
            L.u[0] = loQuad ? c0 : d0_; L.u[1] = loQuad ? c1 : d1;
            L.u[2] = loQuad ? c2 : d2;  L.u[3] = loQuad ? c3 : d3;
            pfh = H.v; pfl = L.v;
        }
        // ---- main: acc[d] += D x P  (D A-frags from LDS, 2 halves)
#pragma unroll
        for (int half = 0; half < 2; half++) {
            bf16x8 dfh[4], dfl[4];
#pragma unroll
            for (int i = 0; i < 4; i++) {
                const int row = ((half*4 + i)*16 + l15) * DLSTR;
                dfh[i] = ld8(&Ds[row + qd*8]);
                dfl[i] = ld8(&Ds[row + 32 + qd*8]);
            }
#pragma unroll
            for (int i = 0; i < 4; i++) {
                acc[half*4+i] = __builtin_amdgcn_mfma_f32_16x16x32_bf16(
                    dfh[i], pfh, acc[half*4+i], 0, 0, 0);
                acc[half*4+i] = __builtin_amdgcn_mfma_f32_16x16x32_bf16(
                    dfh[i], pfl, acc[half*4+i], 0, 0, 0);
                acc[half*4+i] = __builtin_amdgcn_mfma_f32_16x16x32_bf16(
                    dfl[i], pfh, acc[half*4+i], 0, 0, 0);
            }
        }
        __syncthreads();   // chunk fully consumed before next staging
    }

    // ---- finalize row sums: reduce across quads (lane bits 4,5)
    rs += __shfl_xor(rs, 16);
    rs += __shfl_xor(rs, 32);

    const float lam = 1.f / (1.f + __expf(-llam[0]));
    const float oml = 1.f - lam;
    bf16_t* DToutg = (FINAL ? (bf16_t*)nullptr : DTout + (size_t)bh * TDS);

    {
        const int t = Tw + l15;              // C col (global t)
        const float s = lam / rs;
#pragma unroll
        for (int it = 0; it < 8; it++) {
            const int d0 = it*16 + qd*4;     // C rows d0..d0+3
            float v[4];
#pragma unroll
            for (int r = 0; r < 4; r++) {
                const size_t ro = (size_t)(d0 + r)*2048 + t;
                float res = (float)DTh[ro] + (float)DTh[ro + 1024];
                v[r] = oml*res + s*acc[it][r];
            }
            if (FINAL) {
                *(float4*)&Dc[((size_t)bh*Tc + t)*128 + d0] =
                    make_float4(v[0], v[1], v[2], v[3]);
            } else {
#pragma unroll
                for (int r = 0; r < 4; r++) {
                    const size_t ro = (size_t)(d0 + r)*2048 + t;
                    bf16_t h = (bf16_t)v[r];
                    DToutg[ro]        = h;
                    DToutg[ro + 1024] = (bf16_t)(v[r] - (float)h);
                }
            }
        }
    }
}

// ---------------------------------------------------------------------------
// mean over T per (b,h,d)  — D in combined [bh][t][128] f32 layout
// ---------------------------------------------------------------------------
__global__ __launch_bounds__(256)
void mean_k(const float* __restrict__ D,
            float* __restrict__ Mre, float* __restrict__ Mim)
{
    __shared__ float sre[4][64], sim[4][64];
    const int bh = blockIdx.x;
    const int d = threadIdx.x & 63, q = threadIdx.x >> 6;
    const float* p = D + (size_t)bh * TD2;
    float ar = 0.f, ai = 0.f;
    for (int t = q*256; t < q*256 + 256; t++) {
        ar += p[t*128 + d]; ai += p[t*128 + 64 + d];
    }
    sre[q][d] = ar; sim[q][d] = ai;
    __syncthreads();
    if (threadIdx.x < 64) {
        float r  = sre[0][d]+sre[1][d]+sre[2][d]+sre[3][d];
        float im = sim[0][d]+sim[1][d]+sim[2][d]+sim[3][d];
        Mre[bh*64 + d] = r  * (1.f/1024.f);
        Mim[bh*64 + d] = im * (1.f/1024.f);
    }
}

// ---------------------------------------------------------------------------
// gate softmax over T + value gating; gateV emitted as bf16 hi/lo pair
// ---------------------------------------------------------------------------
__global__ __launch_bounds__(256)
void gate_k(const float* __restrict__ D,
            const float* __restrict__ Mre, const float* __restrict__ Mim,
            const float* __restrict__ V,
            float* __restrict__ gate_out,
             bf16_t* __restrict__ gVh, bf16_t* __restrict__ gVl)
{
    __shared__ float part[4][64];
    __shared__ float dinv[64];
    const int bh = blockIdx.x;
    const int d = threadIdx.x & 63, q = threadIdx.x >> 6;
    const float* p = D + (size_t)bh * TD2;
    const float mre = Mre[bh*64 + d], mim = Mim[bh*64 + d];
    const float mabs = sqrtf(mre*mre + mim*mim);

    float ps = 0.f;
    for (int t = q*256; t < (q+1)*256; t++) {
        float dr = p[t*128 + d], dv = p[t*128 + 64 + d];
        float c = (dr*mre + dv*mim) / (sqrtf(dr*dr + dv*dv)*mabs + 1e-8f);
        ps += __expf(c);
    }
    part[q][d] = ps;
    __syncthreads();
    if (threadIdx.x < 64)
        dinv[d] = 1.f / (part[0][d]+part[1][d]+part[2][d]+part[3][d]);
    __syncthreads();

    const float di_ = dinv[d];
    const int b = bh >> 4, hh = bh & 15;
    const float* pv = V + (size_t)bh * TD;
    for (int t = q*256; t < (q+1)*256; t++) {
        float dr = p[t*128 + d], dv = p[t*128 + 64 + d];
        float c = (dr*mre + dv*mim) / (sqrtf(dr*dr + dv*dv)*mabs + 1e-8f);
        float g = __expf(c) * di_;
        gate_out[(size_t)bh*TD + t*64 + d] = g;
        float gv = g * pv[t*64 + d];
        size_t o = ((size_t)b*Tc + t)*DMc + hh*64 + d;
        bf16_t gh = (bf16_t)gv;
        gVh[o] = gh;
        gVl[o] = (bf16_t)(gv - (float)gh);
    }
}

// ---------------------------------------------------------------------------
extern "C" void kernel_launch(void* const* d_in, const int* in_sizes, int n_in,
                              void* d_out, int out_size, void* d_ws, size_t ws_size,
                              hipStream_t stream)
{
    const float* x    = (const float*)d_in[0];
    const float* W_Q  = (const float*)d_in[1];
    const float* W_K  = (const float*)d_in[2];
    const float* W_re = (const float*)d_in[3];
    const float* W_im = (const float*)d_in[4];
    const float* W_V  = (const float*)d_in[5];
    const float* W_O  = (const float*)d_in[6];
    const float* llam = (const float*)d_in[7];

    float* out      = (float*)d_out;
    float* gate_out = out + (size_t)Mc * DMc;

    float* ws = (float*)d_ws;
    const size_t M1 = 1024*1024;
    float*  Dc  = ws;                          // 32 MB — aliases DT1
    bf16_t* DT1 = (bf16_t*)ws;                 // 16M bf16
    bf16_t* DT0 = (bf16_t*)(ws + 8*M1);        // 16M bf16 (32 MB)
    float*  V   = ws + 16*M1;                  // 16 MB
    bf16_t* Qs  = (bf16_t*)(ws + 20*M1);       // 16 MB
    bf16_t* Ksb = (bf16_t*)(ws + 24*M1);       // 16 MB
    float*  Mre = ws + 28*M1;
    float*  Mim = Mre + 4096;
    bf16_t* xh  = (bf16_t*)(ws + 28*M1 + 8192);// 8 MB
    bf16_t* xl  = xh + 4*M1;                   // 8 MB
    bf16_t* WT  = xl + 4*M1;                   // 24 MB
    bf16_t* gVh = xh;                          // alias: x dead after mgemm<0>
    bf16_t* gVl = xl;
    // K-slice partials for mgemm<1>: CONTIGUOUS 16M f32 at ws+8M1, spanning
    // DT0 (8..16), V (16..20, dead after gate_k), Qs (20..24, dead after prop).
    // mgemm<1> writes slice z at P + z*4M1 — matches these pointers exactly.
    float* P0 = ws + 8*M1;
    float* P1 = ws + 12*M1;
    float* P2 = ws + 16*M1;
    float* P3 = ws + 20*M1;

    convx_k<<<4096, 256, 0, stream>>>(x, xh, xl);
    convw_k<<<dim3(32, 32, 6), 256, 0, stream>>>(
        W_Q, W_K, W_re, W_im, W_V, W_O, WT);

    // projections: Q,K -> split slabs; Dre/Dim -> DT0 (transposed split); V f32
    mgemm_k<0><<<dim3(32, 40), 256, 0, stream>>>(
        xh, xl, WT, Qs, Ksb, DT0, V, nullptr);

    prop_k<0><<<dim3(64, 16), 256, 0, stream>>>(Qs, Ksb, DT0, DT1, nullptr, llam);
    prop_k<0><<<dim3(64, 16), 256, 0, stream>>>(Qs, Ksb, DT1, DT0, nullptr, llam);
    prop_k<1><<<dim3(64, 16), 256, 0, stream>>>(Qs, Ksb, DT0, nullptr, Dc, llam);

    mean_k<<<64, 256, 0, stream>>>(Dc, Mre, Mim);
    gate_k<<<64, 256, 0, stream>>>(Dc, Mre, Mim, V, gate_out, gVh, gVl);

    // out = gateV @ W_O, K-split x4 into contiguous partials, then reduce
    mgemm_k<1><<<dim3(32, 8, 4), 256, 0, stream>>>(
        gVh, gVl, WT, nullptr, nullptr, nullptr, nullptr, P0);
    reduce4_k<<<4096, 256, 0, stream>>>(P0, P1, P2, P3, out);
}

// Round 10
// 778.297 us; speedup vs baseline: 1.1396x; 1.1396x over previous
//
#include <hip/hip_runtime.h>
#include <math.h>

// Problem constants
#define Bc 4
#define Tc 1024
#define DMc 1024
#define Hc 16
#define DKc 64
#define BHc 64          // B*H
#define Mc 4096         // B*T
#define TD (Tc*DKc)     // 65536 el per (b,h) slab, stride-64 layout
#define TD2 (Tc*128)    // combined re|im slab, stride-128 layout
#define TDS (128*2048)  // split-D slab: [d(128)][s hi 1024 | s lo 1024] bf16

typedef __bf16 bf16_t;
typedef bf16_t bf16x4 __attribute__((ext_vector_type(4)));
typedef bf16_t bf16x8 __attribute__((ext_vector_type(8)));
typedef float  f32x4  __attribute__((ext_vector_type(4)));

#define GSTR 40    // mgemm: LDS stride for 32-wide rows (80 B)
#define KLSTR 136  // prop: K tile row stride (bf16): [hi 64|lo 64|pad 8]
#define DLSTR 72   // prop: D tile row stride (bf16): [hi 32|lo 32|pad 8]

__device__ __forceinline__ bf16x8 ld8(const bf16_t* p) {
    union { bf16x8 v; struct { bf16x4 a, b; } s; } u;
    u.s.a = *(const bf16x4*)p;
    u.s.b = *(const bf16x4*)(p + 4);
    return u.v;
}
__device__ __forceinline__ void packsplit4(bf16_t* dh, bf16_t* dl, float4 v) {
    bf16x4 h, l;
    h[0]=(bf16_t)v.x; l[0]=(bf16_t)(v.x-(float)h[0]);
    h[1]=(bf16_t)v.y; l[1]=(bf16_t)(v.y-(float)h[1]);
    h[2]=(bf16_t)v.z; l[2]=(bf16_t)(v.z-(float)h[2]);
    h[3]=(bf16_t)v.w; l[3]=(bf16_t)(v.w-(float)h[3]);
    *(bf16x4*)dh = h; *(bf16x4*)dl = l;
}
__device__ __forceinline__ unsigned pk2(bf16_t a, bf16_t b) {
    unsigned short ua = __builtin_bit_cast(unsigned short, a);
    unsigned short ub = __builtin_bit_cast(unsigned short, b);
    return (unsigned)ua | ((unsigned)ub << 16);
}

// ---------------------------------------------------------------------------
// Convert x (4096x1024 f32) -> xh, xl bf16
// ---------------------------------------------------------------------------
__global__ __launch_bounds__(256)
void convx_k(const float* __restrict__ x,
             bf16_t* __restrict__ xh, bf16_t* __restrict__ xl)
{
    size_t i = ((size_t)blockIdx.x * 256 + threadIdx.x) * 4;
    float4 v = *(const float4*)&x[i];
    packsplit4(&xh[i], &xl[i], v);
}

// ---------------------------------------------------------------------------
// Convert + transpose each W (1024x1024 f32 [k][n]) -> WT hi/lo bf16 [n][k].
// ---------------------------------------------------------------------------
__global__ __launch_bounds__(256)
void convw_k(const float* __restrict__ W0, const float* __restrict__ W1,
             const float* __restrict__ W2, const float* __restrict__ W3,
             const float* __restrict__ W4, const float* __restrict__ W5,
             bf16_t* __restrict__ WT)
{
    __shared__ float tile[32][33];
    const float* Ws[6] = {W0, W1, W2, W3, W4, W5};
    const int wi = blockIdx.z;
    const float* W = Ws[wi];
    bf16_t* WTh = WT + (size_t)wi * 2097152;
    bf16_t* WTl = WTh + 1048576;

    const int tx = threadIdx.x & 31, ty = threadIdx.x >> 5;
    const int k0 = blockIdx.x * 32, n0 = blockIdx.y * 32;
#pragma unroll
    for (int i = 0; i < 4; i++)
        tile[ty + 8*i][tx] = W[(size_t)(k0 + ty + 8*i) * DMc + n0 + tx];
    __syncthreads();
    const int kg = threadIdx.x & 7, n = threadIdx.x >> 3;
    float4 v = make_float4(tile[kg*4+0][n], tile[kg*4+1][n],
                           tile[kg*4+2][n], tile[kg*4+3][n]);
    const size_t o = (size_t)(n0 + n) * DMc + k0 + kg*4;
    packsplit4(&WTh[o], &WTl[o], v);
}

// ---------------------------------------------------------------------------
// Split-bf16 MFMA GEMM (3 products, f32 accum). A [m][k] hi/lo; B = WT [n][k].
// MODE 0: sel 0->Qs split [bh][t][hi64|lo64]; 1->Ks same;
//         2,3 -> DT0 split-transposed [bh][d][s hi|lo] (re d 0-63 / im 64-127);
//         4 -> V f32 [bh][t][64].
// MODE 1: K-split x4 (blockIdx.z selects K=256 slice), f32 partial at
//         Of + z*4M floats (CONTIGUOUS slices); reduced by reduce4_k.
// ---------------------------------------------------------------------------
template<int MODE>
__global__ __launch_bounds__(256)
void mgemm_k(const bf16_t* __restrict__ Ah, const bf16_t* __restrict__ Al,
             const bf16_t* __restrict__ WT,
             bf16_t* __restrict__ Oq, bf16_t* __restrict__ Ok,
             bf16_t* __restrict__ Od, float* __restrict__ Ov,
             float* __restrict__ Of)
{
    __shared__ bf16_t Ash[128*GSTR], Asl[128*GSTR];
    __shared__ bf16_t Bsh[128*GSTR], Bsl[128*GSTR];

    const int tid = threadIdx.x;
    const int wv  = tid >> 6;
    const int ln  = tid & 63;
    const int l15 = ln & 15;
    const int qd  = ln >> 4;
    const int m0  = blockIdx.x * 128;
    const int by  = blockIdx.y;

    const bf16_t *Bh, *Bl;
    int n0, sel, kt0, kt1;
    float* Opart;
    if (MODE == 0) {
        sel = by >> 3;
        n0 = (by & 7) * 128;
        Bh = WT + (size_t)sel * 2097152;
        Bl = Bh + 1048576;
        kt0 = 0; kt1 = DMc;
        Opart = nullptr;
    } else {
        sel = 5;
        Bh = WT + (size_t)5 * 2097152;
        Bl = Bh + 1048576;
        n0 = by * 128;
        kt0 = blockIdx.z * 256; kt1 = kt0 + 256;
        Opart = Of + (size_t)blockIdx.z * ((size_t)Mc * DMc);
    }

    const int srow  = tid >> 1;
    const int shalf = (tid & 1) * 16;

    f32x4 acc[4][4];
#pragma unroll
    for (int i = 0; i < 4; i++)
#pragma unroll
        for (int j = 0; j < 4; j++) acc[i][j] = (f32x4)0.f;

#pragma unroll 1
    for (int kt = kt0; kt < kt1; kt += 32) {
        __syncthreads();
        {
            const size_t ga = (size_t)(m0 + srow) * DMc + kt + shalf;
            bf16x8 a0 = *(const bf16x8*)&Ah[ga];
            bf16x8 a1 = *(const bf16x8*)&Ah[ga + 8];
            bf16x8 a2 = *(const bf16x8*)&Al[ga];
            bf16x8 a3 = *(const bf16x8*)&Al[ga + 8];
            const size_t gb = (size_t)(n0 + srow) * DMc + kt + shalf;
            bf16x8 b0 = *(const bf16x8*)&Bh[gb];
            bf16x8 b1 = *(const bf16x8*)&Bh[gb + 8];
            bf16x8 b2 = *(const bf16x8*)&Bl[gb];
            bf16x8 b3 = *(const bf16x8*)&Bl[gb + 8];
            const int lo = srow * GSTR + shalf;
            *(bf16x8*)&Ash[lo]     = a0;
            *(bf16x8*)&Ash[lo + 8] = a1;
            *(bf16x8*)&Asl[lo]     = a2;
            *(bf16x8*)&Asl[lo + 8] = a3;
            *(bf16x8*)&Bsh[lo]     = b0;
            *(bf16x8*)&Bsh[lo + 8] = b1;
            *(bf16x8*)&Bsl[lo]     = b2;
            *(bf16x8*)&Bsl[lo + 8] = b3;
        }
        __syncthreads();

        bf16x8 fah[4], fal[4], fbh[4], fbl[4];
#pragma unroll
        for (int it = 0; it < 4; it++) {
            const int row = ((wv>>1)*64 + it*16 + l15) * GSTR + qd*8;
            fah[it] = ld8(&Ash[row]);
            fal[it] = ld8(&Asl[row]);
        }
#pragma unroll
        for (int jt = 0; jt < 4; jt++) {
            const int row = ((wv&1)*64 + jt*16 + l15) * GSTR + qd*8;
            fbh[jt] = ld8(&Bsh[row]);
            fbl[jt] = ld8(&Bsl[row]);
        }
#pragma unroll
        for (int it = 0; it < 4; it++)
#pragma unroll
            for (int jt = 0; jt < 4; jt++) {
                acc[it][jt] = __builtin_amdgcn_mfma_f32_16x16x32_bf16(
                    fah[it], fbh[jt], acc[it][jt], 0, 0, 0);
                acc[it][jt] = __builtin_amdgcn_mfma_f32_16x16x32_bf16(
                    fah[it], fbl[jt], acc[it][jt], 0, 0, 0);
                acc[it][jt] = __builtin_amdgcn_mfma_f32_16x16x32_bf16(
                    fal[it], fbh[jt], acc[it][jt], 0, 0, 0);
            }
    }

#pragma unroll
    for (int it = 0; it < 4; it++) {
        const int mb = m0 + (wv>>1)*64 + it*16 + qd*4;
#pragma unroll
        for (int jt = 0; jt < 4; jt++) {
            const int col = n0 + (wv&1)*64 + jt*16 + l15;
            if (MODE == 0) {
                const int hh = col >> 6;
                const int b  = mb >> 10, t0 = mb & 1023;
                if (sel <= 1) {
                    bf16_t* O = sel ? Ok : Oq;
                    const int d = col & 63;
#pragma unroll
                    for (int r = 0; r < 4; r++) {
                        const float val = acc[it][jt][r];
                        const size_t o = ((size_t)(b*Hc + hh)*Tc + t0 + r)*128 + d;
                        bf16_t vh = (bf16_t)val;
                        O[o]      = vh;
                        O[o + 64] = (bf16_t)(val - (float)vh);
                    }
                } else if (sel <= 3) {
                    // transposed split-D: [bh][d][t hi | t lo]
                    const int d = (sel == 3 ? 64 : 0) + (col & 63);
                    bf16x4 h4, l4;
#pragma unroll
                    for (int r = 0; r < 4; r++) {
                        const float val = acc[it][jt][r];
                        h4[r] = (bf16_t)val;
                        l4[r] = (bf16_t)(val - (float)h4[r]);
                    }
                    const size_t o = (size_t)(b*Hc + hh)*TDS + (size_t)d*2048 + t0;
                    *(bf16x4*)&Od[o]        = h4;
                    *(bf16x4*)&Od[o + 1024] = l4;
                } else {
#pragma unroll
                    for (int r = 0; r < 4; r++)
                        Ov[((size_t)(b*Hc + hh)*Tc + t0 + r)*64 + (col & 63)]
                            = acc[it][jt][r];
                }
            } else {
#pragma unroll
                for (int r = 0; r < 4; r++)
                    Opart[(size_t)(mb + r) * DMc + col] = acc[it][jt][r];
            }
        }
    }
}

// ---------------------------------------------------------------------------
// Sum 4 K-slice partials -> out
// ---------------------------------------------------------------------------
__global__ __launch_bounds__(256)
void reduce4_k(const float* __restrict__ p0, const float* __restrict__ p1,
               const float* __restrict__ p2, const float* __restrict__ p3,
               float* __restrict__ out)
{
    size_t i = ((size_t)blockIdx.x * 256 + threadIdx.x) * 4;
    float4 a = *(const float4*)&p0[i];
    float4 b = *(const float4*)&p1[i];
    float4 c = *(const float4*)&p2[i];
    float4 d = *(const float4*)&p3[i];
    *(float4*)&out[i] = make_float4(a.x+b.x+c.x+d.x, a.y+b.y+c.y+d.y,
                                    a.z+b.z+c.z+d.z, a.w+b.w+c.w+d.w);
}

// ---------------------------------------------------------------------------
// Fused propagation step: split-bf16 MFMA, r7 structure (measured best):
// 128-t blocks, 32 t's per wave, grid (64, 8) -> 2 blocks/CU.
// K/D tiles staged in LDS (pure 16B copies of pre-split data); scores
// computed transposed (A=K, B=Q -> C[s][t]) with Q fragments in registers;
// P stays in registers, moved to B-operand layout via __shfl (verified r6).
// 2 barriers per 32-s chunk. Row-sums finalized with 2 shfl_xor.
// Layouts: Q/K [bh][t|s][hi64|lo64]; D [bh][d 0..127][s hi 1024 | s lo 1024].
// FINAL=0: out split-D slab.  FINAL=1: out Dc f32 [bh][t][128].
// ---------------------------------------------------------------------------
template<int FINAL>
__global__ __launch_bounds__(256)
void prop_k(const bf16_t* __restrict__ Qg, const bf16_t* __restrict__ Kg,
            const bf16_t* __restrict__ DTin, bf16_t* __restrict__ DTout,
            float* __restrict__ Dc, const float* __restrict__ llam)
{
    __shared__ bf16_t Ks[32*KLSTR];    // 8.7 KB: [s][dk hi 64 | dk lo 64 | pad]
    __shared__ bf16_t Ds[128*DLSTR];   // 18.4 KB: [d][s hi 32 | s lo 32 | pad]

    const int tid = threadIdx.x;
    const int wv  = tid >> 6;
    const int ln  = tid & 63;
    const int l15 = ln & 15;
    const int qd  = ln >> 4;
    const int bh  = blockIdx.x;
    const int Tw  = blockIdx.y * 128 + wv * 32;   // this wave's 32 t's

    const bf16_t* Qh  = Qg   + (size_t)bh * (Tc*128);
    const bf16_t* Kh  = Kg   + (size_t)bh * (Tc*128);
    const bf16_t* DTh = DTin + (size_t)bh * TDS;

    // Q B-fragments (lane n=t=l15, k=dk=qd*8+j), loop-invariant
    bf16x8 qfh[2][2], qfl[2][2];     // [tj][ks]
#pragma unroll
    for (int tj = 0; tj < 2; tj++) {
        const bf16_t* qp = &Qh[(size_t)(Tw + tj*16 + l15) * 128];
#pragma unroll
        for (int ks = 0; ks < 2; ks++) {
            qfh[tj][ks] = *(const bf16x8*)&qp[ks*32 + qd*8];
            qfl[tj][ks] = *(const bf16x8*)&qp[64 + ks*32 + qd*8];
        }
    }

    f32x4 acc[8][2];                 // [d-tile][t-tile]
#pragma unroll
    for (int i = 0; i < 8; i++)
#pragma unroll
        for (int j = 0; j < 2; j++) acc[i][j] = (f32x4)0.f;
    float rs[2] = {0.f, 0.f};

    // shfl source lanes for the P layout transform (verified r6)
    const int srcA = (((qd & 1) * 2)     << 4) | l15;
    const int srcB = (((qd & 1) * 2 + 1) << 4) | l15;
    const bool loQuad = (qd < 2);

#pragma unroll 1
    for (int ch = 0; ch < 32; ch++) {
        const int s0 = ch * 32;
        // ---- stage K chunk (32 x [hi64|lo64], contiguous in global)
#pragma unroll
        for (int i = 0; i < 2; i++) {
            int id = tid + i*256;
            int r = id >> 4, sg = id & 15;
            *(bf16x8*)&Ks[r*KLSTR + sg*8] =
                *(const bf16x8*)&Kh[(size_t)(s0 + r)*128 + sg*8];
        }
        // ---- stage D chunk (128 x [s hi 32 | s lo 32])
#pragma unroll
        for (int i = 0; i < 4; i++) {
            int id = tid + i*256;
            int r = id >> 3, sg = id & 7;
            const bf16_t* src = (sg < 4)
                ? &DTh[(size_t)r*2048 + s0 + sg*8]
                : &DTh[(size_t)r*2048 + 1024 + s0 + (sg-4)*8];
            bf16_t* dst = (sg < 4) ? &Ds[r*DLSTR + sg*8]
                                   : &Ds[r*DLSTR + 32 + (sg-4)*8];
            *(bf16x8*)dst = *(const bf16x8*)src;
        }
        __syncthreads();
        // ---- K A-fragments from LDS (lane m=s=si*16+l15, k=dk)
        bf16x8 kfh[2][2], kfl[2][2];   // [si][ks]
#pragma unroll
        for (int si = 0; si < 2; si++) {
            const int row = (si*16 + l15) * KLSTR;
#pragma unroll
            for (int ks = 0; ks < 2; ks++) {
                kfh[si][ks] = ld8(&Ks[row + ks*32 + qd*8]);
                kfl[si][ks] = ld8(&Ks[row + 64 + ks*32 + qd*8]);
            }
        }
        // ---- scores^T: C[m=s][n=t]
        f32x4 pacc[2][2];              // [si][tj]
#pragma unroll
        for (int si = 0; si < 2; si++)
#pragma unroll
            for (int tj = 0; tj < 2; tj++) pacc[si][tj] = (f32x4)0.f;
#pragma unroll
        for (int ks = 0; ks < 2; ks++)
#pragma unroll
            for (int si = 0; si < 2; si++)
#pragma unroll
                for (int tj = 0; tj < 2; tj++) {
                    pacc[si][tj] = __builtin_amdgcn_mfma_f32_16x16x32_bf16(
                        kfh[si][ks], qfh[tj][ks], pacc[si][tj], 0, 0, 0);
                    pacc[si][tj] = __builtin_amdgcn_mfma_f32_16x16x32_bf16(
                        kfl[si][ks], qfh[tj][ks], pacc[si][tj], 0, 0, 0);
                    pacc[si][tj] = __builtin_amdgcn_mfma_f32_16x16x32_bf16(
                        kfh[si][ks], qfl[tj][ks], pacc[si][tj], 0, 0, 0);
                }
        // ---- exp + split + pack (lane holds s = si*16 + qd*4 + r for t=l15)
        unsigned pk01h[2][2], pk23h[2][2], pk01l[2][2], pk23l[2][2]; // [si][tj]
#pragma unroll
        for (int si = 0; si < 2; si++)
#pragma unroll
            for (int tj = 0; tj < 2; tj++) {
                float e0 = __expf(pacc[si][tj][0] * 0.125f);
                float e1 = __expf(pacc[si][tj][1] * 0.125f);
                float e2 = __expf(pacc[si][tj][2] * 0.125f);
                float e3 = __expf(pacc[si][tj][3] * 0.125f);
                rs[tj] += (e0 + e1) + (e2 + e3);
                bf16_t h0=(bf16_t)e0, h1=(bf16_t)e1, h2=(bf16_t)e2, h3=(bf16_t)e3;
                pk01h[si][tj] = pk2(h0, h1);
                pk23h[si][tj] = pk2(h2, h3);
                pk01l[si][tj] = pk2((bf16_t)(e0-(float)h0), (bf16_t)(e1-(float)h1));
                pk23l[si][tj] = pk2((bf16_t)(e2-(float)h2), (bf16_t)(e3-(float)h3));
            }
        // ---- P -> B-operand fragments via shfl (dest: n=t=l15, k=s=qd*8+j)
        bf16x8 pfh[2], pfl[2];
#pragma unroll
        for (int tj = 0; tj < 2; tj++) {
            union { bf16x8 v; unsigned u[4]; } H, L;
            unsigned a0 = __shfl((int)pk01h[0][tj], srcA, 64);
            unsigned a1 = __shfl((int)pk23h[0][tj], srcA, 64);
            unsigned a2 = __shfl((int)pk01h[0][tj], srcB, 64);
            unsigned a3 = __shfl((int)pk23h[0][tj], srcB, 64);
            unsigned b0 = __shfl((int)pk01h[1][tj], srcA, 64);
            unsigned b1 = __shfl((int)pk23h[1][tj], srcA, 64);
            unsigned b2 = __shfl((int)pk01h[1][tj], srcB, 64);
            unsigned b3 = __shfl((int)pk23h[1][tj], srcB, 64);
            H.u[0] = loQuad ? a0 : b0;  H.u[1] = loQuad ? a1 : b1;
            H.u[2] = loQuad ? a2 : b2;  H.u[3] = loQuad ? a3 : b3;
            unsigned c0 = __shfl((int)pk01l[0][tj], srcA, 64);
            unsigned c1 = __shfl((int)pk23l[0][tj], srcA, 64);
            unsigned c2 = __shfl((int)pk01l[0][tj], srcB, 64);
            unsigned c3 = __shfl((int)pk23l[0][tj], srcB, 64);
            unsigned d0_ = __shfl((int)pk01l[1][tj], srcA, 64);
            unsigned d1 = __shfl((int)pk23l[1][tj], srcA, 64);
            unsigned d2 = __shfl((int)pk01l[1][tj], srcB, 64);
            unsigned d3 = __shfl((int)pk23l[1][tj], srcB, 64);
            L.u[0] = loQuad ? c0 : d0_; L.u[1] = loQuad ? c1 : d1;
            L.u[2] = loQuad ? c2 : d2;  L.u[3] = loQuad ? c3 : d3;
            pfh[tj] = H.v; pfl[tj] = L.v;
        }
        // ---- main: acc[d][t] += D x P  (D A-frags from LDS, 2 halves)
#pragma unroll
        for (int half = 0; half < 2; half++) {
            bf16x8 dfh[4], dfl[4];
#pragma unroll
            for (int i = 0; i < 4; i++) {
                const int row = ((half*4 + i)*16 + l15) * DLSTR;
                dfh[i] = ld8(&Ds[row + qd*8]);
                dfl[i] = ld8(&Ds[row + 32 + qd*8]);
            }
#pragma unroll
            for (int i = 0; i < 4; i++)
#pragma unroll
                for (int tj = 0; tj < 2; tj++) {
                    acc[half*4+i][tj] = __builtin_amdgcn_mfma_f32_16x16x32_bf16(
                        dfh[i], pfh[tj], acc[half*4+i][tj], 0, 0, 0);
                    acc[half*4+i][tj] = __builtin_amdgcn_mfma_f32_16x16x32_bf16(
                        dfh[i], pfl[tj], acc[half*4+i][tj], 0, 0, 0);
                    acc[half*4+i][tj] = __builtin_amdgcn_mfma_f32_16x16x32_bf16(
                        dfl[i], pfh[tj], acc[half*4+i][tj], 0, 0, 0);
                }
        }
        __syncthreads();   // chunk fully consumed before next staging
    }

    // ---- finalize row sums: reduce across quads (lane bits 4,5)
#pragma unroll
    for (int tj = 0; tj < 2; tj++) {
        rs[tj] += __shfl_xor(rs[tj], 16);
        rs[tj] += __shfl_xor(rs[tj], 32);
    }

    const float lam = 1.f / (1.f + __expf(-llam[0]));
    const float oml = 1.f - lam;
    bf16_t* DToutg = (FINAL ? (bf16_t*)nullptr : DTout + (size_t)bh * TDS);

#pragma unroll
    for (int tj = 0; tj < 2; tj++) {
        const int t = Tw + tj*16 + l15;          // C col (global t)
        const float s = lam / rs[tj];
#pragma unroll
        for (int it = 0; it < 8; it++) {
            const int d0 = it*16 + qd*4;         // C rows d0..d0+3
            float v[4];
#pragma unroll
            for (int r = 0; r < 4; r++) {
                const size_t ro = (size_t)(d0 + r)*2048 + t;
                float res = (float)DTh[ro] + (float)DTh[ro + 1024];
                v[r] = oml*res + s*acc[it][tj][r];
            }
            if (FINAL) {
                *(float4*)&Dc[((size_t)bh*Tc + t)*128 + d0] =
                    make_float4(v[0], v[1], v[2], v[3]);
            } else {
#pragma unroll
                for (int r = 0; r < 4; r++) {
                    const size_t ro = (size_t)(d0 + r)*2048 + t;
                    bf16_t h = (bf16_t)v[r];
                    DToutg[ro]        = h;
                    DToutg[ro + 1024] = (bf16_t)(v[r] - (float)h);
                }
            }
        }
    }
}

// ---------------------------------------------------------------------------
// mean over T per (b,h,d)  — D in combined [bh][t][128] f32 layout
// ---------------------------------------------------------------------------
__global__ __launch_bounds__(256)
void mean_k(const float* __restrict__ D,
            float* __restrict__ Mre, float* __restrict__ Mim)
{
    __shared__ float sre[4][64], sim[4][64];
    const int bh = blockIdx.x;
    const int d = threadIdx.x & 63, q = threadIdx.x >> 6;
    const float* p = D + (size_t)bh * TD2;
    float ar = 0.f, ai = 0.f;
    for (int t = q*256; t < q*256 + 256; t++) {
        ar += p[t*128 + d]; ai += p[t*128 + 64 + d];
    }
    sre[q][d] = ar; sim[q][d] = ai;
    __syncthreads();
    if (threadIdx.x < 64) {
        float r  = sre[0][d]+sre[1][d]+sre[2][d]+sre[3][d];
        float im = sim[0][d]+sim[1][d]+sim[2][d]+sim[3][d];
        Mre[bh*64 + d] = r  * (1.f/1024.f);
        Mim[bh*64 + d] = im * (1.f/1024.f);
    }
}

// ---------------------------------------------------------------------------
// gate softmax over T + value gating; gateV emitted as bf16 hi/lo pair
// ---------------------------------------------------------------------------
__global__ __launch_bounds__(256)
void gate_k(const float* __restrict__ D,
            const float* __restrict__ Mre, const float* __restrict__ Mim,
            const float* __restrict__ V,
            float* __restrict__ gate_out,
             bf16_t* __restrict__ gVh, bf16_t* __restrict__ gVl)
{
    __shared__ float part[4][64];
    __shared__ float dinv[64];
    const int bh = blockIdx.x;
    const int d = threadIdx.x & 63, q = threadIdx.x >> 6;
    const float* p = D + (size_t)bh * TD2;
    const float mre = Mre[bh*64 + d], mim = Mim[bh*64 + d];
    const float mabs = sqrtf(mre*mre + mim*mim);

    float ps = 0.f;
    for (int t = q*256; t < (q+1)*256; t++) {
        float dr = p[t*128 + d], dv = p[t*128 + 64 + d];
        float c = (dr*mre + dv*mim) / (sqrtf(dr*dr + dv*dv)*mabs + 1e-8f);
        ps += __expf(c);
    }
    part[q][d] = ps;
    __syncthreads();
    if (threadIdx.x < 64)
        dinv[d] = 1.f / (part[0][d]+part[1][d]+part[2][d]+part[3][d]);
    __syncthreads();

    const float di_ = dinv[d];
    const int b = bh >> 4, hh = bh & 15;
    const float* pv = V + (size_t)bh * TD;
    for (int t = q*256; t < (q+1)*256; t++) {
        float dr = p[t*128 + d], dv = p[t*128 + 64 + d];
        float c = (dr*mre + dv*mim) / (sqrtf(dr*dr + dv*dv)*mabs + 1e-8f);
        float g = __expf(c) * di_;
        gate_out[(size_t)bh*TD + t*64 + d] = g;
        float gv = g * pv[t*64 + d];
        size_t o = ((size_t)b*Tc + t)*DMc + hh*64 + d;
        bf16_t gh = (bf16_t)gv;
        gVh[o] = gh;
        gVl[o] = (bf16_t)(gv - (float)gh);
    }
}

// ---------------------------------------------------------------------------
extern "C" void kernel_launch(void* const* d_in, const int* in_sizes, int n_in,
                              void* d_out, int out_size, void* d_ws, size_t ws_size,
                              hipStream_t stream)
{
    const float* x    = (const float*)d_in[0];
    const float* W_Q  = (const float*)d_in[1];
    const float* W_K  = (const float*)d_in[2];
    const float* W_re = (const float*)d_in[3];
    const float* W_im = (const float*)d_in[4];
    const float* W_V  = (const float*)d_in[5];
    const float* W_O  = (const float*)d_in[6];
    const float* llam = (const float*)d_in[7];

    float* out      = (float*)d_out;
    float* gate_out = out + (size_t)Mc * DMc;

    float* ws = (float*)d_ws;
    const size_t M1 = 1024*1024;
    float*  Dc  = ws;                          // 32 MB — aliases DT1
    bf16_t* DT1 = (bf16_t*)ws;                 // 16M bf16
    bf16_t* DT0 = (bf16_t*)(ws + 8*M1);        // 16M bf16 (32 MB)
    float*  V   = ws + 16*M1;                  // 16 MB
    bf16_t* Qs  = (bf16_t*)(ws + 20*M1);       // 16 MB
    bf16_t* Ksb = (bf16_t*)(ws + 24*M1);       // 16 MB
    float*  Mre = ws + 28*M1;
    float*  Mim = Mre + 4096;
    bf16_t* xh  = (bf16_t*)(ws + 28*M1 + 8192);// 8 MB
    bf16_t* xl  = xh + 4*M1;                   // 8 MB
    bf16_t* WT  = xl + 4*M1;                   // 24 MB
    bf16_t* gVh = xh;                          // alias: x dead after mgemm<0>
    bf16_t* gVl = xl;
    // K-slice partials for mgemm<1>: CONTIGUOUS 16M f32 at ws+8M1, spanning
    // DT0 (8..16), V (16..20, dead after gate_k), Qs (20..24, dead after prop).
    float* P0 = ws + 8*M1;
    float* P1 = ws + 12*M1;
    float* P2 = ws + 16*M1;
    float* P3 = ws + 20*M1;

    convx_k<<<4096, 256, 0, stream>>>(x, xh, xl);
    convw_k<<<dim3(32, 32, 6), 256, 0, stream>>>(
        W_Q, W_K, W_re, W_im, W_V, W_O, WT);

    // projections: Q,K -> split slabs; Dre/Dim -> DT0 (transposed split); V f32
    mgemm_k<0><<<dim3(32, 40), 256, 0, stream>>>(
        xh, xl, WT, Qs, Ksb, DT0, V, nullptr);

    prop_k<0><<<dim3(64, 8), 256, 0, stream>>>(Qs, Ksb, DT0, DT1, nullptr, llam);
    prop_k<0><<<dim3(64, 8), 256, 0, stream>>>(Qs, Ksb, DT1, DT0, nullptr, llam);
    prop_k<1><<<dim3(64, 8), 256, 0, stream>>>(Qs, Ksb, DT0, nullptr, Dc, llam);

    mean_k<<<64, 256, 0, stream>>>(Dc, Mre, Mim);
    gate_k<<<64, 256, 0, stream>>>(Dc, Mre, Mim, V, gate_out, gVh, gVl);

    // out = gateV @ W_O, K-split x4 into contiguous partials, then reduce
    mgemm_k<1><<<dim3(32, 8, 4), 256, 0, stream>>>(
        gVh, gVl, WT, nullptr, nullptr, nullptr, nullptr, P0);
    reduce4_k<<<4096, 256, 0, stream>>>(P0, P1, P2, P3, out);
}